// Round 2
// baseline (543.221 us; speedup 1.0000x reference)
//
#include <hip/hip_runtime.h>

typedef _Float16 half8  __attribute__((ext_vector_type(8)));
typedef _Float16 half2v __attribute__((ext_vector_type(2)));
typedef float    f32x4  __attribute__((ext_vector_type(4)));
typedef float    f32x2  __attribute__((ext_vector_type(2)));

#define QLEN  512
#define NS    64
#define LS    128
#define EDIM  256

// P-chunk swizzle: bits 4-5 only (bit>=6 would alias adjacent rows)
#define PSWZ(q) ((((q) ^ ((q) >> 2)) & 3) << 4)

__global__ __launch_bounds__(512, 2)
void DotAttn_20083267076209_kernel(const float* __restrict__ qg,
                                   const float* __restrict__ kg,
                                   const float* __restrict__ vg,
                                   const int*   __restrict__ maskg,
                                   float*       __restrict__ outg)
{
    // K fp16 [128 l][256 e], row stride 512 B, byte = l*512 + (e*2 ^ ((l&7)<<4))
    __shared__ __align__(16) unsigned char kbuf[65536];
    // V^T fp16 [256 e][128 l], row stride 256 B, byte = e*256 + (l*2 ^ (((e>>1)&7)<<4))
    __shared__ __align__(16) unsigned char vbuf[65536];
    // P per-wave fp16 [16 q][32 l-chunk], row stride 64 B, swizzled with PSWZ
    __shared__ __align__(16) unsigned char pbuf[8 * 1024];

    const int tid  = threadIdx.x;
    const int w    = tid >> 6;
    const int lane = tid & 63;
    const int c    = lane & 15;
    const int g    = lane >> 4;

    const int b = blockIdx.x & 7;   // XCD x owns batch x -> Q L2-resident per XCD
    const int s = blockIdx.x >> 3;

    const float* kbase = kg + (size_t)(b * NS + s) * LS * EDIM;
    const float* vbase = vg + (size_t)(b * NS + s) * LS * EDIM;
    const float* qbb   = qg + (size_t)b * QLEN * EDIM;

    // ---- mask bits: bit t = keep(l = t*16 + c) ----
    int mbits = 0;
    {
        const int* mb = maskg + (b * NS + s) * LS;
#pragma unroll
        for (int t = 0; t < 8; ++t)
            if (mb[t * 16 + c] != 0) mbits |= (1 << t);
    }

    // ---- stage K: [128][256] fp32 -> fp16 LDS, coalesced, swizzled ----
#pragma unroll
    for (int it = 0; it < 8; ++it) {
        int f  = it * 4096 + tid * 8;
        int r  = f >> 8;
        int e0 = f & 255;
        const float* src = kbase + (size_t)r * EDIM + e0;
        f32x4 a = *(const f32x4*)src;
        f32x4 d = *(const f32x4*)(src + 4);
        half8 h;
        h[0]=(_Float16)a[0]; h[1]=(_Float16)a[1]; h[2]=(_Float16)a[2]; h[3]=(_Float16)a[3];
        h[4]=(_Float16)d[0]; h[5]=(_Float16)d[1]; h[6]=(_Float16)d[2]; h[7]=(_Float16)d[3];
        *(half8*)(kbuf + r * 512 + ((e0 * 2) ^ ((r & 7) << 4))) = h;
    }

    // ---- stage V^T: coalesced f32x2 reads, transposed swizzled fp16 writes ----
    {
        int p    = tid & 127;   // e-pair index
        int loct = tid >> 7;    // l-octet 0..3
#pragma unroll
        for (int jj = 0; jj < 4; ++jj) {
            int lb0 = jj * 32 + loct * 8;
            half8 h0, h1;
#pragma unroll
            for (int j = 0; j < 8; ++j) {
                f32x2 t2 = *(const f32x2*)(vbase + (size_t)(lb0 + j) * EDIM + 2 * p);
                h0[j] = (_Float16)t2[0];
                h1[j] = (_Float16)t2[1];
            }
            int e0 = 2 * p;
            int sw = (p & 7) << 4;           // ((e>>1)&7)<<4, same for the row pair
            *(half8*)(vbuf + (e0    ) * 256 + ((lb0 * 2) ^ sw)) = h0;
            *(half8*)(vbuf + (e0 + 1) * 256 + ((lb0 * 2) ^ sw)) = h1;
        }
    }
    __syncthreads();   // the only barrier: K/V are read-only below, P is wave-private

    unsigned char* pw = pbuf + w * 1024;

#pragma unroll 1
    for (int qi = 0; qi < 4; ++qi) {
        const int qrow0 = qi * 128 + w * 16;

        // ---- Q A-frags: global fp32 -> fp16 regs. A[row=c][k = ks*32 + g*8 + j] ----
        half8 qf[8];
#pragma unroll
        for (int ks = 0; ks < 8; ++ks) {
            const float* p = qbb + (size_t)(qrow0 + c) * EDIM + ks * 32 + g * 8;
            f32x4 a = *(const f32x4*)p;
            f32x4 d = *(const f32x4*)(p + 4);
            half8 h;
            h[0]=(_Float16)a[0]; h[1]=(_Float16)a[1]; h[2]=(_Float16)a[2]; h[3]=(_Float16)a[3];
            h[4]=(_Float16)d[0]; h[5]=(_Float16)d[1]; h[6]=(_Float16)d[2]; h[7]=(_Float16)d[3];
            qf[ks] = h;
        }

        // ---- S = Q K^T ----
        f32x4 sacc[8];
#pragma unroll
        for (int t = 0; t < 8; ++t) sacc[t] = (f32x4){0.f, 0.f, 0.f, 0.f};
#pragma unroll
        for (int lt = 0; lt < 4; ++lt) {
#pragma unroll
            for (int lb = 0; lb < 2; ++lb) {
                int row  = lt * 32 + lb * 16 + c;
                int base = row * 512;
                int sw   = (c & 7) << 4;     // row&7 == c&7
#pragma unroll
                for (int ks = 0; ks < 8; ++ks) {
                    half8 bf = *(const half8*)(kbuf + base + ((ks * 64 + g * 16) ^ sw));
                    sacc[lt * 2 + lb] =
                        __builtin_amdgcn_mfma_f32_16x16x32_f16(qf[ks], bf, sacc[lt * 2 + lb], 0, 0, 0);
                }
            }
        }

        // ---- mask + softmax over l (row q = 4g+r, col l = t*16+c) ----
#pragma unroll
        for (int t = 0; t < 8; ++t)
            if (!((mbits >> t) & 1)) {
                sacc[t][0] = -1e30f; sacc[t][1] = -1e30f;
                sacc[t][2] = -1e30f; sacc[t][3] = -1e30f;
            }
#pragma unroll
        for (int r = 0; r < 4; ++r) {
            float m = sacc[0][r];
#pragma unroll
            for (int t = 1; t < 8; ++t) m = fmaxf(m, sacc[t][r]);
            m = fmaxf(m, __shfl_xor(m, 1, 64));
            m = fmaxf(m, __shfl_xor(m, 2, 64));
            m = fmaxf(m, __shfl_xor(m, 4, 64));
            m = fmaxf(m, __shfl_xor(m, 8, 64));
            float sum = 0.f;
#pragma unroll
            for (int t = 0; t < 8; ++t) {
                float pp = __expf(sacc[t][r] - m);
                sacc[t][r] = pp;
                sum += pp;
            }
            sum += __shfl_xor(sum, 1, 64);
            sum += __shfl_xor(sum, 2, 64);
            sum += __shfl_xor(sum, 4, 64);
            sum += __shfl_xor(sum, 8, 64);
            float inv = 1.f / sum;
#pragma unroll
            for (int t = 0; t < 8; ++t) sacc[t][r] *= inv;
        }

        // ---- O = P V, P through wave-private 1 KB LDS chunk per 32-l slice ----
        f32x4 oacc[16];
#pragma unroll
        for (int et = 0; et < 16; ++et) oacc[et] = (f32x4){0.f, 0.f, 0.f, 0.f};

#pragma unroll
        for (int lt = 0; lt < 4; ++lt) {
            // write P cols [lt*32, lt*32+32): pack fp16 pairs, even-c lanes store 4 B
#pragma unroll
            for (int th = 0; th < 2; ++th) {
#pragma unroll
                for (int r = 0; r < 4; ++r) {
                    float v  = sacc[lt * 2 + th][r];
                    float vn = __shfl_xor(v, 1, 64);
                    if (!(c & 1)) {
                        half2v h2; h2[0] = (_Float16)v; h2[1] = (_Float16)vn;
                        int q    = 4 * g + r;
                        int col2 = (th * 16 + c) * 2;
                        *(half2v*)(pw + q * 64 + (col2 ^ PSWZ(q))) = h2;
                    }
                }
            }
            // A-frag: P[q=c][l-chunk col = g*8 + j]
            half8 af = *(const half8*)(pw + c * 64 + ((g * 16) ^ PSWZ(c)));
#pragma unroll
            for (int et = 0; et < 16; ++et) {
                int e = et * 16 + c;
                half8 bf = *(const half8*)(vbuf + e * 256 +
                                           ((lt * 64 + g * 16) ^ (((e >> 1) & 7) << 4)));
                oacc[et] = __builtin_amdgcn_mfma_f32_16x16x32_f16(af, bf, oacc[et], 0, 0, 0);
            }
        }

        // ---- epilogue: out[b][q][s][e], q = qrow0 + 4g + r, e = et*16 + c ----
        float* ob = outg + (((size_t)b * QLEN + qrow0 + 4 * g) * NS + s) * EDIM + c;
#pragma unroll
        for (int et = 0; et < 16; ++et) {
#pragma unroll
            for (int r = 0; r < 4; ++r)
                ob[(size_t)r * NS * EDIM + et * 16] = oacc[et][r];
        }
    }
}

extern "C" void kernel_launch(void* const* d_in, const int* in_sizes, int n_in,
                              void* d_out, int out_size, void* d_ws, size_t ws_size,
                              hipStream_t stream) {
    const float* q    = (const float*)d_in[0];
    const float* k    = (const float*)d_in[1];
    const float* v    = (const float*)d_in[2];
    const int*   mask = (const int*)d_in[3];
    float* out = (float*)d_out;
    dim3 grid(8 * NS);    // 512 blocks: b = bid&7, s = bid>>3
    dim3 block(512);
    hipLaunchKernelGGL(DotAttn_20083267076209_kernel, grid, block, 0, stream,
                       q, k, v, mask, out);
}

// Round 3
// 166.630 us; speedup vs baseline: 3.2600x; 3.2600x over previous
//
#include <hip/hip_runtime.h>

typedef _Float16 half8  __attribute__((ext_vector_type(8)));
typedef _Float16 half2v __attribute__((ext_vector_type(2)));
typedef float    f32x4  __attribute__((ext_vector_type(4)));
typedef float    f32x2  __attribute__((ext_vector_type(2)));

#define QLEN  512
#define NS    64
#define LS    128
#define EDIM  256
#define QT    64

// ---- K staging: chunk = 32 l-rows x 256 e fp16 (16 KB), double-buffered ----
#define KLOAD(dst, lt) do {                                                   \
  _Pragma("unroll") for (int it = 0; it < 4; ++it) {                          \
    int f = it * 2048 + tid * 8; int r = f >> 8; int e0 = f & 255;            \
    const float* src = kbase + (size_t)((lt) * 32 + r) * EDIM + e0;           \
    dst[2*it]   = *(const f32x4*)src;                                         \
    dst[2*it+1] = *(const f32x4*)(src + 4); } } while (0)

#define KSTORE(sv, bi) do {                                                   \
  _Pragma("unroll") for (int it = 0; it < 4; ++it) {                          \
    int f = it * 2048 + tid * 8; int r = f >> 8; int e0 = f & 255;            \
    f32x4 a = sv[2*it], d = sv[2*it+1]; half8 h;                              \
    h[0]=(_Float16)a[0]; h[1]=(_Float16)a[1]; h[2]=(_Float16)a[2]; h[3]=(_Float16)a[3]; \
    h[4]=(_Float16)d[0]; h[5]=(_Float16)d[1]; h[6]=(_Float16)d[2]; h[7]=(_Float16)d[3]; \
    *(half8*)(kvbuf + (bi) * 16384 + r * 512 + ((e0 * 2) ^ ((r & 7) << 4))) = h; } } while (0)

// ---- V staging: V^T [256 e][64 l] fp16 (32 KB), rows 128 B, two halves ----
#define VLOAD(d, lt) do {                                                     \
  _Pragma("unroll") for (int jj = 0; jj < 2; ++jj)                            \
  _Pragma("unroll") for (int j = 0; j < 8; ++j) {                             \
    int l = (lt) * 32 + vlh * 16 + jj * 8 + j;                                \
    d[jj*8+j] = *(const f32x2*)(vbase + (size_t)l * EDIM + 2 * vp); } } while (0)

#define VSTORE(sv, lt) do {                                                   \
  _Pragma("unroll") for (int jj = 0; jj < 2; ++jj) {                          \
    half8 h0, h1;                                                             \
    _Pragma("unroll") for (int j = 0; j < 8; ++j) {                           \
      h0[j] = (_Float16)sv[jj*8+j][0]; h1[j] = (_Float16)sv[jj*8+j][1]; }     \
    int l0 = (((lt) & 1) * 32 + vlh * 16 + jj * 8) * 2;                       \
    int sw = (vp & 7) << 4;                                                   \
    *(half8*)(kvbuf + (2*vp    ) * 128 + (l0 ^ sw)) = h0;                     \
    *(half8*)(kvbuf + (2*vp + 1) * 128 + (l0 ^ sw)) = h1; } } while (0)

#define PV(lt) do {                                                           \
  half8 af = *(const half8*)(pw + c * 256 + ((((lt) * 64) + g * 16) ^ (c << 4))); \
  _Pragma("unroll") for (int et = 0; et < 16; ++et) {                         \
    int e = et * 16 + c;                                                      \
    half8 bf = *(const half8*)(kvbuf + e * 128 +                              \
                 (((((lt) & 1) * 64) + g * 16) ^ (((e >> 1) & 7) << 4)));     \
    oacc[et] = __builtin_amdgcn_mfma_f32_16x16x32_f16(af, bf, oacc[et], 0, 0, 0); } } while (0)

__global__ __launch_bounds__(256, 3)
void DotAttn_20083267076209_kernel(const float* __restrict__ qg,
                                   const float* __restrict__ kg,
                                   const float* __restrict__ vg,
                                   const int*   __restrict__ maskg,
                                   float*       __restrict__ outg)
{
    // union: K double-buffer 2x16KB  /  V^T [256][64] 32KB
    __shared__ __align__(16) unsigned char kvbuf[32768];
    // P per wave: [16 q][128 l] fp16, row 256 B, byte = q*256 + ((2l) ^ (q<<4))
    __shared__ __align__(16) unsigned char pbuf[4][4096];

    const int tid  = threadIdx.x;
    const int w    = tid >> 6;
    const int lane = tid & 63;
    const int c    = lane & 15;
    const int g    = lane >> 4;
    const int vp   = tid & 127;   // e-pair index for V staging
    const int vlh  = tid >> 7;    // l-half within V chunk

    // XCD-bijective decode: all 8 qt-sharers of (b,s) land on the same XCD
    const int bid = blockIdx.x;
    const int xcd = bid & 7;
    const int qt  = (bid >> 3) & 7;
    const int b   = (bid >> 6) & 7;
    const int s   = (bid >> 9) * 8 + xcd;

    const float* kbase = kg + (size_t)(b * NS + s) * LS * EDIM;
    const float* vbase = vg + (size_t)(b * NS + s) * LS * EDIM;
    const float* qbase = qg + ((size_t)b * QLEN + (size_t)qt * QT + (size_t)w * 16) * EDIM;
    unsigned char* pw  = pbuf[w];

    // mask bits: bit t = keep(l = t*16 + c)
    int mbits = 0;
    {
        const int* mb = maskg + (b * NS + s) * LS;
#pragma unroll
        for (int t = 0; t < 8; ++t)
            if (mb[t * 16 + c] != 0) mbits |= (1 << t);
    }

    // Q A-frags: A[row=c][k = ks*32 + g*8 + j]
    half8 qf[8];
#pragma unroll
    for (int ks = 0; ks < 8; ++ks) {
        const float* p = qbase + (size_t)c * EDIM + ks * 32 + g * 8;
        f32x4 a = *(const f32x4*)p;
        f32x4 d = *(const f32x4*)(p + 4);
        half8 h;
        h[0]=(_Float16)a[0]; h[1]=(_Float16)a[1]; h[2]=(_Float16)a[2]; h[3]=(_Float16)a[3];
        h[4]=(_Float16)d[0]; h[5]=(_Float16)d[1]; h[6]=(_Float16)d[2]; h[7]=(_Float16)d[3];
        qf[ks] = h;
    }

    // ---- S = Q K^T, pipelined K chunks ----
    f32x4 kr[8];
    f32x2 vrA[16], vrB[16];
    KLOAD(kr, 0);

    f32x4 sacc[8];
#pragma unroll
    for (int t = 0; t < 8; ++t) sacc[t] = (f32x4){0.f, 0.f, 0.f, 0.f};

#pragma unroll
    for (int lt = 0; lt < 4; ++lt) {
        KSTORE(kr, lt & 1);
        if (lt < 3) KLOAD(kr, lt + 1);
        else        VLOAD(vrA, 0);          // V chunk0 prefetch under last K MFMA
        __syncthreads();
        const unsigned char* kb = kvbuf + (lt & 1) * 16384;
#pragma unroll
        for (int lb = 0; lb < 2; ++lb) {
            int row  = lb * 16 + c;
            int base = row * 512;
            int sw   = (c & 7) << 4;
#pragma unroll
            for (int ks = 0; ks < 8; ++ks) {
                half8 bf = *(const half8*)(kb + base + ((ks * 64 + g * 16) ^ sw));
                sacc[lt * 2 + lb] =
                    __builtin_amdgcn_mfma_f32_16x16x32_f16(qf[ks], bf, sacc[lt * 2 + lb], 0, 0, 0);
            }
        }
    }

    // ---- mask + softmax (row q = 4g+r, col l = t*16+c) ----
#pragma unroll
    for (int t = 0; t < 8; ++t)
        if (!((mbits >> t) & 1)) {
            sacc[t][0] = -1e30f; sacc[t][1] = -1e30f;
            sacc[t][2] = -1e30f; sacc[t][3] = -1e30f;
        }
#pragma unroll
    for (int r = 0; r < 4; ++r) {
        float m = sacc[0][r];
#pragma unroll
        for (int t = 1; t < 8; ++t) m = fmaxf(m, sacc[t][r]);
        m = fmaxf(m, __shfl_xor(m, 1, 64));
        m = fmaxf(m, __shfl_xor(m, 2, 64));
        m = fmaxf(m, __shfl_xor(m, 4, 64));
        m = fmaxf(m, __shfl_xor(m, 8, 64));
        float sum = 0.f;
#pragma unroll
        for (int t = 0; t < 8; ++t) {
            float pp = __expf(sacc[t][r] - m);
            sacc[t][r] = pp;
            sum += pp;
        }
        sum += __shfl_xor(sum, 1, 64);
        sum += __shfl_xor(sum, 2, 64);
        sum += __shfl_xor(sum, 4, 64);
        sum += __shfl_xor(sum, 8, 64);
        float inv = 1.f / sum;
#pragma unroll
        for (int t = 0; t < 8; ++t) sacc[t][r] *= inv;
    }

    // ---- P -> wave-private LDS, fp16 packed via lane pairing ----
#pragma unroll
    for (int t = 0; t < 8; ++t) {
#pragma unroll
        for (int r = 0; r < 4; ++r) {
            float v  = sacc[t][r];
            float vn = __shfl_xor(v, 1, 64);
            if (!(c & 1)) {
                half2v h2; h2[0] = (_Float16)v; h2[1] = (_Float16)vn;
                int q = 4 * g + r;
                *(half2v*)(pw + q * 256 + ((2 * (t * 16 + c)) ^ (q << 4))) = h2;
            }
        }
    }

    VLOAD(vrB, 1);        // chunk1 in flight across the barrier
    __syncthreads();      // all waves done with K MFMA; kvbuf becomes V^T

    f32x4 oacc[16];
#pragma unroll
    for (int et = 0; et < 16; ++et) oacc[et] = (f32x4){0.f, 0.f, 0.f, 0.f};

    // half 0: chunks 0,1 staged; chunks 2,3 prefetched under the MFMA
    VSTORE(vrA, 0);
    VSTORE(vrB, 1);
    VLOAD(vrA, 2);
    VLOAD(vrB, 3);
    __syncthreads();
    PV(0);
    PV(1);
    __syncthreads();      // all waves done reading half 0
    VSTORE(vrA, 2);
    VSTORE(vrB, 3);
    __syncthreads();
    PV(2);
    PV(3);

    // ---- epilogue (R0-proven): out[b][q][s][e], q = qt*64 + w*16 + 4g + r ----
    float* ob = outg + (((size_t)b * QLEN + (size_t)qt * QT + w * 16 + 4 * g) * NS + s) * EDIM + c;
#pragma unroll
    for (int et = 0; et < 16; ++et) {
#pragma unroll
        for (int r = 0; r < 4; ++r)
            ob[(size_t)r * NS * EDIM + et * 16] = oacc[et][r];
    }
}

extern "C" void kernel_launch(void* const* d_in, const int* in_sizes, int n_in,
                              void* d_out, int out_size, void* d_ws, size_t ws_size,
                              hipStream_t stream) {
    const float* q    = (const float*)d_in[0];
    const float* k    = (const float*)d_in[1];
    const float* v    = (const float*)d_in[2];
    const int*   mask = (const int*)d_in[3];
    float* out = (float*)d_out;
    dim3 grid(4096);
    dim3 block(256);
    hipLaunchKernelGGL(DotAttn_20083267076209_kernel, grid, block, 0, stream,
                       q, k, v, mask, out);
}